// Round 4
// baseline (150.310 us; speedup 1.0000x reference)
//
#include <hip/hip_runtime.h>
#include <hip/hip_cooperative_groups.h>

namespace cg = cooperative_groups;

// MoE B=4096, D=256, H=1024, E=8, fp32 in/out, bf16 MFMA internally.
// Single persistent cooperative kernel, 256 blocks x 512 threads (1 block/CU):
//  P0: bin tokens (LDS histogram) || transpose+convert W1 -> w1t[e][h][d] bf16
//  P1: gather x -> xg[e][pos][d] bf16 || transpose+convert W2 -> w2t[e][d][h]
//  P2: GEMM1 h = relu(xg @ w1t^T + b1) -> hw bf16   (jobs: 8e x 16t x 8 h-chunks of 128)
//  P3: GEMM2 out[token] = hw @ w2t^T + b2           (jobs: 8e x 16t x 2 d-chunks of 128)

#define D_DIM 256
#define H_DIM 1024
#define E_NUM 8
#define B_TOK 4096
#define CAP   1024

typedef __attribute__((ext_vector_type(8))) short short8;
typedef __attribute__((ext_vector_type(4))) float f32x4;
typedef unsigned short u16;
typedef unsigned int u32;
typedef unsigned long long u64;

// ws layout (bytes)
#define CNT_OFF    0
#define BUCKET_OFF 1024
#define XG_OFF     (BUCKET_OFF + E_NUM*B_TOK*4)
#define W1T_OFF    (XG_OFF  + (size_t)E_NUM*CAP*D_DIM*2)
#define W2T_OFF    (W1T_OFF + (size_t)E_NUM*H_DIM*D_DIM*2)
#define HW_OFF     (W2T_OFF + (size_t)E_NUM*D_DIM*H_DIM*2)

// LDS element offsets (u16 elems)
#define XS_EL   0        // [64][264]
#define W1S_EL  16896    // [128][264]
#define HS_EL   50688    // [64][136]
#define SMEM_EL 59392    // 118784 B

__device__ __forceinline__ u16 f2bf(float f) {
    u32 u = __builtin_bit_cast(u32, f);
    u = (u + 0x7fffu + ((u >> 16) & 1u)) >> 16;  // RNE
    return (u16)u;
}

// 64x64 fp32->bf16 transpose tile. C = input row stride, R = output row stride.
// 256 threads (tt). Contains 2 __syncthreads (block-uniform callers only!).
__device__ __forceinline__ void trans64(const float* __restrict__ in,
                                        u16* __restrict__ outp,
                                        int R, int C, int rt, int ct,
                                        int tt, u16* tile) {
    #pragma unroll
    for (int it = 0; it < 4; ++it) {
        int r = it * 16 + (tt >> 4);
        int c4 = (tt & 15) * 4;
        float4 v = *(const float4*)(in + (size_t)(rt * 64 + r) * C + ct * 64 + c4);
        u64 pk = (u64)f2bf(v.x) | ((u64)f2bf(v.y) << 16)
               | ((u64)f2bf(v.z) << 32) | ((u64)f2bf(v.w) << 48);
        *(u64*)&tile[r * 68 + c4] = pk;
    }
    __syncthreads();
    #pragma unroll
    for (int it = 0; it < 2; ++it) {
        int oc = it * 32 + (tt >> 3);
        int r0 = (tt & 7) * 8;
        u32 p0 = tile[(r0 + 0) * 68 + oc] | ((u32)tile[(r0 + 1) * 68 + oc] << 16);
        u32 p1 = tile[(r0 + 2) * 68 + oc] | ((u32)tile[(r0 + 3) * 68 + oc] << 16);
        u32 p2 = tile[(r0 + 4) * 68 + oc] | ((u32)tile[(r0 + 5) * 68 + oc] << 16);
        u32 p3 = tile[(r0 + 6) * 68 + oc] | ((u32)tile[(r0 + 7) * 68 + oc] << 16);
        *(uint4*)(outp + (size_t)(ct * 64 + oc) * R + rt * 64 + r0) = uint4{p0, p1, p2, p3};
    }
    __syncthreads();
}

__global__ __launch_bounds__(512, 2) void moe_persistent(
    const float* __restrict__ x, const float* __restrict__ W1,
    const float* __restrict__ b1, const float* __restrict__ W2,
    const float* __restrict__ b2, const int* __restrict__ eidx,
    int* cnt, int* bucket, u16* xg, u16* w1t, u16* w2t, u16* hw,
    float* __restrict__ out)
{
    __shared__ u16 smem[SMEM_EL];
    __shared__ int lcnt[E_NUM], lbase[E_NUM];

    cg::grid_group grid = cg::this_grid();
    const int bid = blockIdx.x;
    const int tid = threadIdx.x;
    const int half = tid >> 8, tt = tid & 255;

    // ================= P0: bin (blocks 0..7) + W1 transpose =================
    if (bid < 8) {
        if (tid < E_NUM) lcnt[tid] = 0;
        __syncthreads();
        int t = bid * 512 + tid;                 // 8*512 = 4096 tokens exactly
        int e = eidx[t];
        int lp = atomicAdd(&lcnt[e], 1);         // LDS atomic
        __syncthreads();
        if (tid < E_NUM) lbase[tid] = atomicAdd(&cnt[tid], lcnt[tid]);
        __syncthreads();
        bucket[e * B_TOK + lbase[e] + lp] = t;
    }
    {
        int job = bid * 2 + half;                // 0..511  (W1: [256d][1024h] -> [h][d])
        int e = job >> 6, tj = job & 63;
        int rt = tj >> 4, ct = tj & 15;          // rt over D/64=4, ct over H/64=16
        trans64(W1 + (size_t)e * D_DIM * H_DIM,
                w1t + (size_t)e * H_DIM * D_DIM,
                D_DIM, H_DIM, rt, ct, tt, smem + half * 4352);
    }
    grid.sync();

    // ================= P1: gather x -> xg  + W2 transpose =================
    {
        int wid = bid * 8 + (tid >> 6);
        int lane = tid & 63;
        #pragma unroll
        for (int i = 0; i < 4; ++i) {
            int row = wid * 4 + i;               // 0..8191
            int e = row >> 10, pos = row & (CAP - 1);
            int n = min(cnt[e], CAP);
            u64 pk = 0;
            if (pos < n) {
                int tk = bucket[e * B_TOK + pos];
                float4 v = *(const float4*)(x + (size_t)tk * D_DIM + lane * 4);
                pk = (u64)f2bf(v.x) | ((u64)f2bf(v.y) << 16)
                   | ((u64)f2bf(v.z) << 32) | ((u64)f2bf(v.w) << 48);
            }
            *(u64*)&xg[(size_t)row * D_DIM + lane * 4] = pk;
        }
    }
    {
        int job = bid * 2 + half;                // 0..511  (W2: [1024h][256d] -> [d][h])
        int e = job >> 6, tj = job & 63;
        int rt = tj >> 2, ct = tj & 3;           // rt over H/64=16, ct over D/64=4
        trans64(W2 + (size_t)e * H_DIM * D_DIM,
                w2t + (size_t)e * D_DIM * H_DIM,
                H_DIM, D_DIM, rt, ct, tt, smem + half * 4352);
    }
    grid.sync();

    // ================= P2: GEMM1  h = relu(x @ W1 + b1) =================
    {
        int p = bid >> 1;
        int e = p >> 4, t = p & 15, hh = bid & 1;
        int n = min(cnt[e], CAP);
        if (t * 64 < n) {
            u16* xs  = smem + XS_EL;
            u16* w1s = smem + W1S_EL;
            u16* hs  = smem + HS_EL;
            const int w = tid >> 6, L = tid & 63, l15 = L & 15, l4 = L >> 4;
            const int m0 = (w >> 2) * 32, n0 = (w & 3) * 32;

            const u16* gx = xg + ((size_t)e * CAP + t * 64) * D_DIM;
            #pragma unroll
            for (int it = 0; it < 4; ++it) {
                int id = it * 512 + tid;
                int row = id >> 5, cc = (id & 31) * 8;
                *(short8*)&xs[row * 264 + cc] = *(const short8*)&gx[(size_t)row * D_DIM + cc];
            }

            for (int j = 0; j < 4; ++j) {
                int hch = hh * 4 + j;            // 128-wide h chunk
                const u16* gw = w1t + ((size_t)e * H_DIM + hch * 128) * D_DIM;
                #pragma unroll
                for (int it = 0; it < 8; ++it) {
                    int id = it * 512 + tid;
                    int row = id >> 5, cc = (id & 31) * 8;
                    *(short8*)&w1s[row * 264 + cc] = *(const short8*)&gw[(size_t)row * D_DIM + cc];
                }
                __syncthreads();

                f32x4 acc[2][2];
                #pragma unroll
                for (int a = 0; a < 2; ++a)
                    #pragma unroll
                    for (int c = 0; c < 2; ++c) acc[a][c] = (f32x4){0.f, 0.f, 0.f, 0.f};
                #pragma unroll
                for (int k = 0; k < 8; ++k) {
                    short8 a0 = *(const short8*)&xs[(m0 + l15) * 264 + k * 32 + l4 * 8];
                    short8 a1 = *(const short8*)&xs[(m0 + 16 + l15) * 264 + k * 32 + l4 * 8];
                    short8 b0 = *(const short8*)&w1s[(n0 + l15) * 264 + k * 32 + l4 * 8];
                    short8 b1v = *(const short8*)&w1s[(n0 + 16 + l15) * 264 + k * 32 + l4 * 8];
                    acc[0][0] = __builtin_amdgcn_mfma_f32_16x16x32_bf16(a0, b0, acc[0][0], 0, 0, 0);
                    acc[0][1] = __builtin_amdgcn_mfma_f32_16x16x32_bf16(a0, b1v, acc[0][1], 0, 0, 0);
                    acc[1][0] = __builtin_amdgcn_mfma_f32_16x16x32_bf16(a1, b0, acc[1][0], 0, 0, 0);
                    acc[1][1] = __builtin_amdgcn_mfma_f32_16x16x32_bf16(a1, b1v, acc[1][1], 0, 0, 0);
                }
                #pragma unroll
                for (int nc = 0; nc < 2; ++nc) {
                    float bias = b1[e * H_DIM + hch * 128 + n0 + nc * 16 + l15];
                    #pragma unroll
                    for (int mr = 0; mr < 2; ++mr)
                        #pragma unroll
                        for (int jj = 0; jj < 4; ++jj) {
                            float v = acc[mr][nc][jj] + bias;
                            v = fmaxf(v, 0.f);
                            hs[(m0 + mr * 16 + l4 * 4 + jj) * 136 + n0 + nc * 16 + l15] = f2bf(v);
                        }
                }
                __syncthreads();
                u16* gh = hw + ((size_t)e * CAP + t * 64) * H_DIM + hch * 128;
                #pragma unroll
                for (int it = 0; it < 2; ++it) {
                    int id = it * 512 + tid;
                    int row = id >> 4, cc = (id & 15) * 8;
                    *(short8*)&gh[(size_t)row * H_DIM + cc] = *(const short8*)&hs[row * 136 + cc];
                }
                __syncthreads();
            }
        }
    }
    grid.sync();

    // ================= P3: GEMM2  out = h @ W2 + b2 (scatter) =================
    {
        int e = bid >> 5, rem = bid & 31;
        int t = rem >> 1, nh = rem & 1;          // d-chunk of 128
        int n = min(cnt[e], CAP);
        if (t * 64 < n) {
            u16* as_ = smem + XS_EL;             // [64][264]
            u16* bs  = smem + W1S_EL;            // [128][264]
            const int w = tid >> 6, L = tid & 63, l15 = L & 15, l4 = L >> 4;
            const int m0 = (w >> 2) * 32, n0 = (w & 3) * 32;

            f32x4 acc[2][2];
            #pragma unroll
            for (int a = 0; a < 2; ++a)
                #pragma unroll
                for (int c = 0; c < 2; ++c) acc[a][c] = (f32x4){0.f, 0.f, 0.f, 0.f};

            const u16* ga = hw + ((size_t)e * CAP + t * 64) * H_DIM;
            const u16* gb = w2t + ((size_t)e * D_DIM + nh * 128) * H_DIM;

            for (int kc = 0; kc < 4; ++kc) {
                __syncthreads();
                #pragma unroll
                for (int it = 0; it < 4; ++it) {
                    int id = it * 512 + tid;
                    int row = id >> 5, cc = (id & 31) * 8;
                    *(short8*)&as_[row * 264 + cc] =
                        *(const short8*)&ga[(size_t)row * H_DIM + kc * 256 + cc];
                }
                #pragma unroll
                for (int it = 0; it < 8; ++it) {
                    int id = it * 512 + tid;
                    int row = id >> 5, cc = (id & 31) * 8;
                    *(short8*)&bs[row * 264 + cc] =
                        *(const short8*)&gb[(size_t)row * H_DIM + kc * 256 + cc];
                }
                __syncthreads();
                #pragma unroll
                for (int k = 0; k < 8; ++k) {
                    short8 a0 = *(const short8*)&as_[(m0 + l15) * 264 + k * 32 + l4 * 8];
                    short8 a1 = *(const short8*)&as_[(m0 + 16 + l15) * 264 + k * 32 + l4 * 8];
                    short8 b0 = *(const short8*)&bs[(n0 + l15) * 264 + k * 32 + l4 * 8];
                    short8 b1v = *(const short8*)&bs[(n0 + 16 + l15) * 264 + k * 32 + l4 * 8];
                    acc[0][0] = __builtin_amdgcn_mfma_f32_16x16x32_bf16(a0, b0, acc[0][0], 0, 0, 0);
                    acc[0][1] = __builtin_amdgcn_mfma_f32_16x16x32_bf16(a0, b1v, acc[0][1], 0, 0, 0);
                    acc[1][0] = __builtin_amdgcn_mfma_f32_16x16x32_bf16(a1, b0, acc[1][0], 0, 0, 0);
                    acc[1][1] = __builtin_amdgcn_mfma_f32_16x16x32_bf16(a1, b1v, acc[1][1], 0, 0, 0);
                }
            }

            #pragma unroll
            for (int mr = 0; mr < 2; ++mr)
                #pragma unroll
                for (int jj = 0; jj < 4; ++jj) {
                    int m = m0 + mr * 16 + l4 * 4 + jj;
                    if (t * 64 + m < n) {
                        int token = bucket[e * B_TOK + t * 64 + m];
                        #pragma unroll
                        for (int nc = 0; nc < 2; ++nc) {
                            int d = nh * 128 + n0 + nc * 16 + l15;
                            out[(size_t)token * D_DIM + d] = acc[mr][nc][jj] + b2[e * D_DIM + d];
                        }
                    }
                }
        }
    }
}

extern "C" void kernel_launch(void* const* d_in, const int* in_sizes, int n_in,
                              void* d_out, int out_size, void* d_ws, size_t ws_size,
                              hipStream_t stream) {
    const float* x  = (const float*)d_in[0];
    const float* W1 = (const float*)d_in[1];
    const float* b1 = (const float*)d_in[2];
    const float* W2 = (const float*)d_in[3];
    const float* b2 = (const float*)d_in[4];
    const int* eidx = (const int*)d_in[5];
    float* out = (float*)d_out;

    char* ws = (char*)d_ws;
    int* cnt    = (int*)(ws + CNT_OFF);
    int* bucket = (int*)(ws + BUCKET_OFF);
    u16* xg     = (u16*)(ws + XG_OFF);
    u16* w1t    = (u16*)(ws + W1T_OFF);
    u16* w2t    = (u16*)(ws + W2T_OFF);
    u16* hw     = (u16*)(ws + HW_OFF);

    hipMemsetAsync(cnt, 0, 8 * sizeof(int), stream);
    void* args[] = {(void*)&x, (void*)&W1, (void*)&b1, (void*)&W2, (void*)&b2,
                    (void*)&eidx, (void*)&cnt, (void*)&bucket, (void*)&xg,
                    (void*)&w1t, (void*)&w2t, (void*)&hw, (void*)&out};
    hipLaunchCooperativeKernel((void*)moe_persistent, dim3(256), dim3(512),
                               args, 0, stream);
}

// Round 5
// 40.098 us; speedup vs baseline: 3.7486x; 3.7486x over previous
//
#include <hip/hip_runtime.h>

// MoE B=4096, D=256, H=1024, E=8. 4 launches:
//  K1 bin: deterministic ballot/prefix scan, 1 block per expert (no memset, no atomics)
//  K2 prep: W1 -> w1t[e][h][d] bf16, W2 -> w2t[e][d][h] bf16, gather x -> xg bf16
//  K3 gemm1: h = relu(xg @ w1t^T + b1) -> hw bf16   (grid 8e x 16t x 16hch)
//  K4 gemm2: out[token] = hw @ w2t^T + b2            (grid 8e x 16t x 4nch)

#define D_DIM 256
#define H_DIM 1024
#define E_NUM 8
#define B_TOK 4096
#define CAP   1024

typedef __attribute__((ext_vector_type(8))) short short8;
typedef __attribute__((ext_vector_type(4))) float f32x4;
typedef unsigned short u16;
typedef unsigned int u32;
typedef unsigned long long u64;

// ws layout (bytes)
#define CNT_OFF    0
#define BUCKET_OFF 1024
#define XG_OFF     (BUCKET_OFF + E_NUM*B_TOK*4)
#define W1T_OFF    (XG_OFF  + (size_t)E_NUM*CAP*D_DIM*2)
#define W2T_OFF    (W1T_OFF + (size_t)E_NUM*H_DIM*D_DIM*2)
#define HW_OFF     (W2T_OFF + (size_t)E_NUM*D_DIM*H_DIM*2)

__device__ __forceinline__ u16 f2bf(float f) {
    u32 u = __builtin_bit_cast(u32, f);
    u = (u + 0x7fffu + ((u >> 16) & 1u)) >> 16;  // RNE
    return (u16)u;
}

// ---- K1: deterministic bin. Block e scans all tokens in order. ----
__global__ __launch_bounds__(1024) void bin_kernel(const int* __restrict__ eidx,
                                                   int* __restrict__ cnt,
                                                   int* __restrict__ bucket) {
    __shared__ int wsum[16], wbase[16];
    __shared__ int base, chunk_total;
    const int e = blockIdx.x, tid = threadIdx.x;
    const int lane = tid & 63, wv = tid >> 6;
    if (tid == 0) base = 0;
    __syncthreads();
    #pragma unroll
    for (int c = 0; c < 4; ++c) {
        int t = c * 1024 + tid;
        bool m = (eidx[t] == e);
        u64 bal = __ballot(m);
        int pfx = __popcll(bal & ((1ull << lane) - 1ull));
        if (lane == 0) wsum[wv] = __popcll(bal);
        __syncthreads();
        if (tid == 0) {
            int s = 0;
            #pragma unroll
            for (int i = 0; i < 16; ++i) { wbase[i] = s; s += wsum[i]; }
            chunk_total = s;
        }
        __syncthreads();
        if (m) bucket[e * B_TOK + base + wbase[wv] + pfx] = t;
        __syncthreads();
        if (tid == 0) base += chunk_total;
        __syncthreads();
    }
    if (tid == 0) cnt[e] = base;
}

// 64x64 fp32->bf16 transpose tile (256 threads, 2 internal syncs)
__device__ __forceinline__ void trans64(const float* __restrict__ in,
                                        u16* __restrict__ outp,
                                        int R, int C, int rt, int ct,
                                        int tt, u16* tile) {
    #pragma unroll
    for (int it = 0; it < 4; ++it) {
        int r = it * 16 + (tt >> 4);
        int c4 = (tt & 15) * 4;
        float4 v = *(const float4*)(in + (size_t)(rt * 64 + r) * C + ct * 64 + c4);
        u64 pk = (u64)f2bf(v.x) | ((u64)f2bf(v.y) << 16)
               | ((u64)f2bf(v.z) << 32) | ((u64)f2bf(v.w) << 48);
        *(u64*)&tile[r * 68 + c4] = pk;
    }
    __syncthreads();
    #pragma unroll
    for (int it = 0; it < 2; ++it) {
        int oc = it * 32 + (tt >> 3);
        int r0 = (tt & 7) * 8;
        u32 p0 = tile[(r0 + 0) * 68 + oc] | ((u32)tile[(r0 + 1) * 68 + oc] << 16);
        u32 p1 = tile[(r0 + 2) * 68 + oc] | ((u32)tile[(r0 + 3) * 68 + oc] << 16);
        u32 p2 = tile[(r0 + 4) * 68 + oc] | ((u32)tile[(r0 + 5) * 68 + oc] << 16);
        u32 p3 = tile[(r0 + 6) * 68 + oc] | ((u32)tile[(r0 + 7) * 68 + oc] << 16);
        *(uint4*)(outp + (size_t)(ct * 64 + oc) * R + rt * 64 + r0) = uint4{p0, p1, p2, p3};
    }
}

// ---- K2: prep = W1 transpose | W2 transpose | gather x ----
__global__ __launch_bounds__(256) void prep_kernel(
    const float* __restrict__ x, const float* __restrict__ W1,
    const float* __restrict__ W2, const int* __restrict__ cnt,
    const int* __restrict__ bucket, u16* __restrict__ xg,
    u16* __restrict__ w1t, u16* __restrict__ w2t)
{
    __shared__ u16 tile[64 * 68];
    const int b = blockIdx.x, tid = threadIdx.x;
    if (b < 512) {                       // W1 [256d][1024h] -> w1t [h][d]
        int e = b >> 6, tj = b & 63;
        trans64(W1 + (size_t)e * D_DIM * H_DIM, w1t + (size_t)e * H_DIM * D_DIM,
                D_DIM, H_DIM, tj >> 4, tj & 15, tid, tile);
    } else if (b < 1024) {               // W2 [1024h][256d] -> w2t [d][h]
        int e = (b - 512) >> 6, tj = (b - 512) & 63;
        trans64(W2 + (size_t)e * H_DIM * D_DIM, w2t + (size_t)e * D_DIM * H_DIM,
                H_DIM, D_DIM, tj >> 2, tj & 3, tid, tile);
    } else {                             // gather: 512 blocks x 16 rows
        int gb = b - 1024;
        int wv = tid >> 6, lane = tid & 63;
        #pragma unroll
        for (int i = 0; i < 4; ++i) {
            int row = gb * 16 + wv * 4 + i;      // 0..8191
            int e = row >> 10, pos = row & (CAP - 1);
            int n = min(cnt[e], CAP);
            u64 pk = 0;
            if (pos < n) {
                int tk = bucket[e * B_TOK + pos];
                float4 v = *(const float4*)(x + (size_t)tk * D_DIM + lane * 4);
                pk = (u64)f2bf(v.x) | ((u64)f2bf(v.y) << 16)
                   | ((u64)f2bf(v.z) << 32) | ((u64)f2bf(v.w) << 48);
            }
            *(u64*)&xg[(size_t)row * D_DIM + lane * 4] = pk;
        }
    }
}

// ---- K3: GEMM1  M=64,N=64,K=256 ----
__global__ __launch_bounds__(256, 2) void gemm1_kernel(
    const u16* __restrict__ xg, const u16* __restrict__ w1t,
    const float* __restrict__ b1, const int* __restrict__ cnt,
    u16* __restrict__ hw)
{
    __shared__ u16 xs[64 * 264];
    __shared__ u16 w1s[64 * 264];
    __shared__ u16 hs[64 * 72];

    int b = blockIdx.x;
    int e = b >> 8, tile = (b >> 4) & 15, hch = b & 15;
    int n = min(cnt[e], CAP);
    if (tile * 64 >= n) return;

    int tid = threadIdx.x;
    int w = tid >> 6, L = tid & 63, l15 = L & 15, l4 = L >> 4;
    int wr = (w >> 1) * 32, wc = (w & 1) * 32;

    {
        const u16* gx = xg + ((size_t)e * CAP + tile * 64) * D_DIM;
        const u16* gw = w1t + ((size_t)e * H_DIM + hch * 64) * D_DIM;
        int rr = tid >> 5, cc = (tid & 31) * 8;
        #pragma unroll
        for (int it = 0; it < 8; ++it) {
            int row = it * 8 + rr;
            *(short8*)&xs[row * 264 + cc]  = *(const short8*)&gx[(size_t)row * D_DIM + cc];
            *(short8*)&w1s[row * 264 + cc] = *(const short8*)&gw[(size_t)row * D_DIM + cc];
        }
    }
    __syncthreads();

    f32x4 acc[2][2];
    #pragma unroll
    for (int i = 0; i < 2; ++i)
        #pragma unroll
        for (int j = 0; j < 2; ++j) acc[i][j] = (f32x4){0.f, 0.f, 0.f, 0.f};

    #pragma unroll
    for (int k = 0; k < 8; ++k) {
        short8 a0 = *(const short8*)&xs[(wr + l15) * 264 + k * 32 + l4 * 8];
        short8 a1 = *(const short8*)&xs[(wr + 16 + l15) * 264 + k * 32 + l4 * 8];
        short8 b0 = *(const short8*)&w1s[(wc + l15) * 264 + k * 32 + l4 * 8];
        short8 b1v = *(const short8*)&w1s[(wc + 16 + l15) * 264 + k * 32 + l4 * 8];
        acc[0][0] = __builtin_amdgcn_mfma_f32_16x16x32_bf16(a0, b0, acc[0][0], 0, 0, 0);
        acc[0][1] = __builtin_amdgcn_mfma_f32_16x16x32_bf16(a0, b1v, acc[0][1], 0, 0, 0);
        acc[1][0] = __builtin_amdgcn_mfma_f32_16x16x32_bf16(a1, b0, acc[1][0], 0, 0, 0);
        acc[1][1] = __builtin_amdgcn_mfma_f32_16x16x32_bf16(a1, b1v, acc[1][1], 0, 0, 0);
    }

    #pragma unroll
    for (int mr = 0; mr < 2; ++mr)
        #pragma unroll
        for (int nc = 0; nc < 2; ++nc) {
            float bias = b1[e * H_DIM + hch * 64 + wc + nc * 16 + l15];
            #pragma unroll
            for (int j = 0; j < 4; ++j) {
                float v = acc[mr][nc][j] + bias;
                v = fmaxf(v, 0.f);
                hs[(wr + mr * 16 + l4 * 4 + j) * 72 + wc + nc * 16 + l15] = f2bf(v);
            }
        }
    __syncthreads();
    {
        u16* gh = hw + ((size_t)e * CAP + tile * 64) * H_DIM + hch * 64;
        int rr8 = tid >> 3, off = (tid & 7) * 8;
        #pragma unroll
        for (int it = 0; it < 2; ++it) {
            int row = it * 32 + rr8;
            *(short8*)&gh[(size_t)row * H_DIM + off] = *(const short8*)&hs[row * 72 + off];
        }
    }
}

// ---- K4: GEMM2  M=64,N=64,K=1024 (4 chunks) ----
__global__ __launch_bounds__(256, 2) void gemm2_kernel(
    const u16* __restrict__ hw, const u16* __restrict__ w2t,
    const float* __restrict__ b2, const int* __restrict__ cnt,
    const int* __restrict__ bucket, float* __restrict__ out)
{
    __shared__ u16 as_[64 * 264];
    __shared__ u16 bs[64 * 264];

    int b = blockIdx.x;
    int e = b >> 6, tile = (b >> 2) & 15, nch = b & 3;
    int n = min(cnt[e], CAP);
    if (tile * 64 >= n) return;

    int tid = threadIdx.x;
    int w = tid >> 6, L = tid & 63, l15 = L & 15, l4 = L >> 4;
    int wr = (w >> 1) * 32, wc = (w & 1) * 32;

    f32x4 acc[2][2];
    #pragma unroll
    for (int i = 0; i < 2; ++i)
        #pragma unroll
        for (int j = 0; j < 2; ++j) acc[i][j] = (f32x4){0.f, 0.f, 0.f, 0.f};

    const u16* ga = hw + ((size_t)e * CAP + tile * 64) * H_DIM;
    const u16* gb = w2t + ((size_t)e * D_DIM + nch * 64) * H_DIM;

    for (int kc = 0; kc < 4; ++kc) {
        __syncthreads();
        int rr = tid >> 5, cc = (tid & 31) * 8;
        #pragma unroll
        for (int it = 0; it < 8; ++it) {
            int row = it * 8 + rr;
            *(short8*)&as_[row * 264 + cc] = *(const short8*)&ga[(size_t)row * H_DIM + kc * 256 + cc];
            *(short8*)&bs[row * 264 + cc]  = *(const short8*)&gb[(size_t)row * H_DIM + kc * 256 + cc];
        }
        __syncthreads();
        #pragma unroll
        for (int k = 0; k < 8; ++k) {
            short8 a0 = *(const short8*)&as_[(wr + l15) * 264 + k * 32 + l4 * 8];
            short8 a1 = *(const short8*)&as_[(wr + 16 + l15) * 264 + k * 32 + l4 * 8];
            short8 b0 = *(const short8*)&bs[(wc + l15) * 264 + k * 32 + l4 * 8];
            short8 b1v = *(const short8*)&bs[(wc + 16 + l15) * 264 + k * 32 + l4 * 8];
            acc[0][0] = __builtin_amdgcn_mfma_f32_16x16x32_bf16(a0, b0, acc[0][0], 0, 0, 0);
            acc[0][1] = __builtin_amdgcn_mfma_f32_16x16x32_bf16(a0, b1v, acc[0][1], 0, 0, 0);
            acc[1][0] = __builtin_amdgcn_mfma_f32_16x16x32_bf16(a1, b0, acc[1][0], 0, 0, 0);
            acc[1][1] = __builtin_amdgcn_mfma_f32_16x16x32_bf16(a1, b1v, acc[1][1], 0, 0, 0);
        }
    }

    #pragma unroll
    for (int mr = 0; mr < 2; ++mr)
        #pragma unroll
        for (int jj = 0; jj < 4; ++jj) {
            int m = wr + mr * 16 + l4 * 4 + jj;
            if (tile * 64 + m < n) {
                int token = bucket[e * B_TOK + tile * 64 + m];
                #pragma unroll
                for (int nc = 0; nc < 2; ++nc) {
                    int d = nch * 64 + wc + nc * 16 + l15;
                    out[(size_t)token * D_DIM + d] = acc[mr][nc][jj] + b2[e * D_DIM + d];
                }
            }
        }
}

extern "C" void kernel_launch(void* const* d_in, const int* in_sizes, int n_in,
                              void* d_out, int out_size, void* d_ws, size_t ws_size,
                              hipStream_t stream) {
    const float* x  = (const float*)d_in[0];
    const float* W1 = (const float*)d_in[1];
    const float* b1 = (const float*)d_in[2];
    const float* W2 = (const float*)d_in[3];
    const float* b2 = (const float*)d_in[4];
    const int* eidx = (const int*)d_in[5];
    float* out = (float*)d_out;

    char* ws = (char*)d_ws;
    int* cnt    = (int*)(ws + CNT_OFF);
    int* bucket = (int*)(ws + BUCKET_OFF);
    u16* xg     = (u16*)(ws + XG_OFF);
    u16* w1t    = (u16*)(ws + W1T_OFF);
    u16* w2t    = (u16*)(ws + W2T_OFF);
    u16* hw     = (u16*)(ws + HW_OFF);

    bin_kernel<<<E_NUM, 1024, 0, stream>>>(eidx, cnt, bucket);
    prep_kernel<<<1536, 256, 0, stream>>>(x, W1, W2, cnt, bucket, xg, w1t, w2t);
    gemm1_kernel<<<E_NUM * 16 * 16, 256, 0, stream>>>(xg, w1t, b1, cnt, hw);
    gemm2_kernel<<<E_NUM * 16 * 4, 256, 0, stream>>>(hw, w2t, b2, cnt, bucket, out);
}